// Round 7
// baseline (236.750 us; speedup 1.0000x reference)
//
#include <hip/hip_runtime.h>
#include <hip/hip_bf16.h>

typedef __attribute__((ext_vector_type(8))) short short8;
typedef __attribute__((ext_vector_type(4))) float f32x4;

static constexpr int B_ = 64;
static constexpr int N_ = 4096;
static constexpr int V_ = 21;
static constexpr int S_ = 50;
static constexpr int E_ = 64;
static constexpr int H_ = 128;
static constexpr int NPAIR = V_ * V_;   // 441
static constexpr int NTAB = NPAIR * S_; // 22050

__device__ __forceinline__ float rcp_(float x) { return __builtin_amdgcn_rcpf(x); }
__device__ __forceinline__ float sigm(float x) { return rcp_(1.0f + __expf(-x)); }
__device__ __forceinline__ float tanh_(float x) {
  float a = fabsf(x);
  float e = __expf(-2.0f * a);
  float t = (1.0f - e) * rcp_(1.0f + e);
  return x < 0.0f ? -t : t;
}
__device__ __forceinline__ unsigned short f2bf(float f) {
  __hip_bfloat16 b = __float2bfloat16(f);
  return *reinterpret_cast<unsigned short*>(&b);
}
__device__ __forceinline__ float bf2f(unsigned short u) {
  return __uint_as_float(((unsigned int)u) << 16);
}

struct Gates { float cv, hv; };
__device__ __forceinline__ Gates gate_combine(const float* __restrict__ sx, int cc,
    float i_p, float o_p, float u_p, float fl_p, float fr_p, float cl, float cr) {
  float gi = sigm(sx[cc] + i_p);
  float go = sigm(sx[128 + cc] + o_p);
  float gu = tanh_(sx[256 + cc] + u_p);
  float fx = sx[384 + cc];
  float fl = sigm(fx + fl_p);
  float fr = sigm(fx + fr_p);
  float cv = fmaf(gi, gu, fmaf(fl, cl, fr * cr));
  Gates g; g.cv = cv; g.hv = go * tanh_(cv);
  return g;
}

// ---- pre0: weight transposes only ----
// blocks 0..31: Wfrag (bf16 MFMA B-frags of U); 32..63: Wt = U k-major [128][512];
// 64..95: Wxt = Wx k-major [128][512]; 96: Wpt = Wp.T [64][128].
__global__ void k_pre0(const float* __restrict__ Ui, const float* __restrict__ Uo,
                       const float* __restrict__ Uu, const float* __restrict__ Uf,
                       const float* __restrict__ Wi, const float* __restrict__ Wo,
                       const float* __restrict__ Wu, const float* __restrict__ Wf,
                       const float* __restrict__ Wp,
                       unsigned short* __restrict__ Wfrag, float* __restrict__ Wt,
                       float* __restrict__ Wxt, float* __restrict__ Wpt) {
  int blk = blockIdx.x, t = threadIdx.x;
  if (blk < 32) {
    int idx = blk * 256 + t;
    int L = idx & 63;
    int K = (idx >> 6) & 3;
    int T = idx >> 8;
    int n = 16 * T + (L & 15);
    int k0 = 32 * K + ((L >> 4) << 3);
    int g = n >> 7, o = n & 127;
    const float* U = (g == 0) ? Ui : (g == 1) ? Uo : (g == 2) ? Uu : Uf;
    unsigned short out[8];
    #pragma unroll
    for (int j = 0; j < 8; ++j) out[j] = f2bf(U[o * 128 + k0 + j]);
    *(int4*)(Wfrag + (size_t)idx * 8) = *(int4*)out;
  } else if (blk < 96) {
    bool isU = blk < 64;
    int base = (((blk & 31)) * 256 + t) * 8;
    int k = base >> 9;
    int col = base & 511;
    int gg = col >> 7, o0 = col & 127;
    const float* M;
    if (isU) M = (gg == 0) ? Ui : (gg == 1) ? Uo : (gg == 2) ? Uu : Uf;
    else     M = (gg == 0) ? Wi : (gg == 1) ? Wo : (gg == 2) ? Wu : Wf;
    float* D = isU ? Wt : Wxt;
    float v[8];
    #pragma unroll
    for (int j = 0; j < 8; ++j) v[j] = M[(o0 + j) * 128 + k];
    *(float4*)(D + base) = *(float4*)v;
    *(float4*)(D + base + 4) = *(float4*)(v + 4);
  } else {
    for (int i = t; i < E_ * H_; i += 256) {
      int e = i >> 7, o = i & 127;
      Wpt[i] = Wp[o * E_ + e];
    }
  }
}

// ---- pre1: leaf (blocks 0..20) + symx (21..70), fully coalesced via Wpt/Wxt ----
__global__ void k_pre1(const float* __restrict__ emb, const float* __restrict__ sym_emb,
                       const float* __restrict__ Wpt, const float* __restrict__ Wxt,
                       const float* __restrict__ bp, const float* __restrict__ bi,
                       const float* __restrict__ bo, const float* __restrict__ bu,
                       const float* __restrict__ bfv,
                       unsigned short* __restrict__ leaf_h8, float* __restrict__ leaf_c,
                       float* __restrict__ symx) {
  int blk = blockIdx.x, t = threadIdx.x;
  __shared__ float x[128];
  if (blk < V_) {
    int v = blk;
    float acc = bp[t];
    if (v != 0) {  // reference zeroes emb row 0
      for (int e = 0; e < E_; ++e) acc = fmaf(emb[v * E_ + e], Wpt[e * 128 + t], acc);
    }
    x[t] = acc;
    __syncthreads();
    float zi = bi[t], zo = bo[t], zu = bu[t];
    for (int k = 0; k < H_; ++k) {
      float xv = x[k];
      const float* wr = Wxt + k * 512;
      zi = fmaf(xv, wr[t], zi);
      zo = fmaf(xv, wr[128 + t], zo);
      zu = fmaf(xv, wr[256 + t], zu);
    }
    float gi = sigm(zi), go = sigm(zo), gu = tanh_(zu);
    float c = gi * gu;
    leaf_c[v * H_ + t] = c;
    leaf_h8[v * H_ + t] = f2bf(go * tanh_(c));
  } else {
    int s = blk - V_;
    float acc = bp[t];
    for (int e = 0; e < E_; ++e) acc = fmaf(sym_emb[s * E_ + e], Wpt[e * 128 + t], acc);
    x[t] = acc;
    __syncthreads();
    float zi = bi[t], zo = bo[t], zu = bu[t], zf = bfv[t];
    for (int k = 0; k < H_; ++k) {
      float xv = x[k];
      const float* wr = Wxt + k * 512;
      zi = fmaf(xv, wr[t], zi);
      zo = fmaf(xv, wr[128 + t], zo);
      zu = fmaf(xv, wr[256 + t], zu);
      zf = fmaf(xv, wr[384 + t], zf);
    }
    size_t base = (size_t)s * 4 * H_;
    symx[base + 0 * H_ + t] = zi;
    symx[base + 1 * H_ + t] = zo;
    symx[base + 2 * H_ + t] = zu;
    symx[base + 3 * H_ + t] = zf;
  }
}

// ---- table phase A: per-pair matvec pre-activations (coalesced via Wt) ----
__global__ void k_tabA(const unsigned short* __restrict__ leaf_h8, const float* __restrict__ Wt,
                       float* __restrict__ za) {
  int p = blockIdx.x, t = threadIdx.x;  // 441 x 128
  int tl = p / V_, tr = p % V_;
  __shared__ float hl[128], hr[128];
  hl[t] = bf2f(leaf_h8[tl * H_ + t]);
  hr[t] = bf2f(leaf_h8[tr * H_ + t]);
  __syncthreads();
  float zi = 0.f, zo = 0.f, zu = 0.f, pfl = 0.f, pfr = 0.f;
  for (int k = 0; k < H_; ++k) {
    float l = hl[k], r = hr[k], ht = l + r;
    const float* wr = Wt + k * 512;
    zi = fmaf(ht, wr[t], zi);
    zo = fmaf(ht, wr[128 + t], zo);
    zu = fmaf(ht, wr[256 + t], zu);
    float wf = wr[384 + t];
    pfl = fmaf(l, wf, pfl);
    pfr = fmaf(r, wf, pfr);
  }
  float* z = za + (size_t)p * 640;
  z[t] = zi; z[128 + t] = zo; z[256 + t] = zu; z[384 + t] = pfl; z[512 + t] = pfr;
}

// ---- table phase B: gate epilogue over 22050 rows + idx1 build ----
__global__ void k_tabB(const float* __restrict__ za, const float* __restrict__ symx,
                       const float* __restrict__ leaf_c,
                       const int* __restrict__ tokens, const int* __restrict__ symbols,
                       unsigned short* __restrict__ tab_h8, float* __restrict__ tab_c,
                       int* __restrict__ idx1) {
  int blk = blockIdx.x, t = threadIdx.x;
  if (blk < NTAB / 2) {
    int row = blk * 2 + (t >> 7);
    int u = t & 127;
    int p = row / S_, s = row - p * S_;
    int tl = p / V_, tr = p - tl * V_;
    const float* z = za + (size_t)p * 640;
    const float* sx = symx + (size_t)s * 512;
    float gi = sigm(sx[u] + z[u]);
    float go = sigm(sx[128 + u] + z[128 + u]);
    float gu = tanh_(sx[256 + u] + z[256 + u]);
    float fx = sx[384 + u];
    float fl = sigm(fx + z[384 + u]);
    float fr = sigm(fx + z[512 + u]);
    float cv = fmaf(gi, gu, fmaf(fl, leaf_c[tl * H_ + u], fr * leaf_c[tr * H_ + u]));
    tab_c[(size_t)row * H_ + u] = cv;
    tab_h8[(size_t)row * H_ + u] = f2bf(go * tanh_(cv));
  } else {
    int g = (blk - NTAB / 2) * 256 + t;
    int b = g >> 11, j = g & 2047;
    idx1[g] = (tokens[b * N_ + 2 * j] * V_ + tokens[b * N_ + 2 * j + 1]) * S_ + symbols[b * (N_ - 1) + j];
  }
}

// ---- fused levels 2+3: block = 32 L2 nodes -> 16 L3 nodes, L2 state stays in LDS ----
__global__ void __launch_bounds__(512, 4) k_lvl23(
    const unsigned short* __restrict__ Wfrag, const float* __restrict__ symx,
    const int* __restrict__ symbols, const int* __restrict__ idx1,
    const unsigned short* __restrict__ gh8, const float* __restrict__ gc,
    unsigned short* __restrict__ h_out8, float* __restrict__ c_out) {
  __shared__ __align__(16) unsigned short Ag[64][136];
  __shared__ __align__(16) unsigned short Bh[32][136];
  __shared__ float Bc[32][132];
  int t = threadIdx.x;
  int w = t >> 6, L = t & 63, q = L >> 4, cL = L & 15;
  int cc = 16 * w + cL;
  int g0 = blockIdx.x * 32;         // first L2 node (m2=1024/row; 32 | 1024 so b fixed)
  int b = g0 >> 10;
  int j2 = g0 & 1023;
  const int* sym_b = symbols + (size_t)b * (N_ - 1);
  const int* gix = idx1 + 2 * g0;

  #pragma unroll
  for (int i = 0; i < 2; ++i) {
    int fid = t + 512 * i;
    int row = fid >> 4, co = (fid & 15) * 8;
    *(int4*)&Ag[row][co] = *(const int4*)(gh8 + (size_t)gix[row] * H_ + co);
  }
  __syncthreads();

  const short8* wf = (const short8*)Wfrag;
  // level 2: two full chunks of 16 nodes; outputs -> LDS (Bh/Bc)
  #pragma unroll
  for (int c = 0; c < 2; ++c) {
    f32x4 acc[2][4];
    #pragma unroll
    for (int r = 0; r < 2; ++r)
      #pragma unroll
      for (int g = 0; g < 4; ++g) acc[r][g] = (f32x4){0.f, 0.f, 0.f, 0.f};
    #pragma unroll
    for (int K = 0; K < 4; ++K) {
      short8 bfr[4];
      #pragma unroll
      for (int g = 0; g < 4; ++g) bfr[g] = wf[(size_t)((w + 8 * g) * 4 + K) * 64 + L];
      short8 a0 = *(const short8*)&Ag[32 * c + cL][K * 32 + q * 8];
      short8 a1 = *(const short8*)&Ag[32 * c + 16 + cL][K * 32 + q * 8];
      #pragma unroll
      for (int g = 0; g < 4; ++g) {
        acc[0][g] = __builtin_amdgcn_mfma_f32_16x16x32_bf16(a0, bfr[g], acc[0][g], 0, 0, 0);
        acc[1][g] = __builtin_amdgcn_mfma_f32_16x16x32_bf16(a1, bfr[g], acc[1][g], 0, 0, 0);
      }
    }
    #pragma unroll
    for (int r = 0; r < 2; ++r) {
      #pragma unroll
      for (int nd = 0; nd < 2; ++nd) {
        int n = 16 * c + 8 * r + 2 * q + nd;  // local L2 node 0..31
        int s = sym_b[2048 + j2 + n];
        const float* sx = symx + (size_t)s * 512;
        float clv = gc[(size_t)gix[2 * n] * H_ + cc];
        float crv = gc[(size_t)gix[2 * n + 1] * H_ + cc];
        Gates gt = gate_combine(sx, cc,
            acc[r][0][2 * nd] + acc[r][0][2 * nd + 1],
            acc[r][1][2 * nd] + acc[r][1][2 * nd + 1],
            acc[r][2][2 * nd] + acc[r][2][2 * nd + 1],
            acc[r][3][2 * nd], acc[r][3][2 * nd + 1], clv, crv);
        Bc[n][cc] = gt.cv;
        Bh[n][cc] = f2bf(gt.hv);
      }
    }
  }
  __syncthreads();
  // level 3: one chunk of 16 nodes from LDS, outputs -> global
  {
    f32x4 acc[2][4];
    #pragma unroll
    for (int r = 0; r < 2; ++r)
      #pragma unroll
      for (int g = 0; g < 4; ++g) acc[r][g] = (f32x4){0.f, 0.f, 0.f, 0.f};
    #pragma unroll
    for (int K = 0; K < 4; ++K) {
      short8 bfr[4];
      #pragma unroll
      for (int g = 0; g < 4; ++g) bfr[g] = wf[(size_t)((w + 8 * g) * 4 + K) * 64 + L];
      short8 a0 = *(const short8*)&Bh[cL][K * 32 + q * 8];
      short8 a1 = *(const short8*)&Bh[16 + cL][K * 32 + q * 8];
      #pragma unroll
      for (int g = 0; g < 4; ++g) {
        acc[0][g] = __builtin_amdgcn_mfma_f32_16x16x32_bf16(a0, bfr[g], acc[0][g], 0, 0, 0);
        acc[1][g] = __builtin_amdgcn_mfma_f32_16x16x32_bf16(a1, bfr[g], acc[1][g], 0, 0, 0);
      }
    }
    #pragma unroll
    for (int r = 0; r < 2; ++r) {
      #pragma unroll
      for (int nd = 0; nd < 2; ++nd) {
        int n = 8 * r + 2 * q + nd;          // local L3 node 0..15
        int G3 = (g0 >> 1) + n;
        int s = sym_b[3072 + (j2 >> 1) + n];
        const float* sx = symx + (size_t)s * 512;
        Gates gt = gate_combine(sx, cc,
            acc[r][0][2 * nd] + acc[r][0][2 * nd + 1],
            acc[r][1][2 * nd] + acc[r][1][2 * nd + 1],
            acc[r][2][2 * nd] + acc[r][2][2 * nd + 1],
            acc[r][3][2 * nd], acc[r][3][2 * nd + 1],
            Bc[2 * n][cc], Bc[2 * n + 1][cc]);
        c_out[(size_t)G3 * H_ + cc] = gt.cv;
        h_out8[(size_t)G3 * H_ + cc] = f2bf(gt.hv);
      }
    }
  }
}

// ---- fused levels 4+5: same structure, dense input ----
__global__ void __launch_bounds__(512, 4) k_lvl45(
    const unsigned short* __restrict__ Wfrag, const float* __restrict__ symx,
    const int* __restrict__ symbols,
    const unsigned short* __restrict__ in_h8, const float* __restrict__ in_c,
    unsigned short* __restrict__ h_out8, float* __restrict__ c_out) {
  __shared__ __align__(16) unsigned short Ag[64][136];
  __shared__ __align__(16) unsigned short Bh[32][136];
  __shared__ float Bc[32][132];
  int t = threadIdx.x;
  int w = t >> 6, L = t & 63, q = L >> 4, cL = L & 15;
  int cc = 16 * w + cL;
  int g0 = blockIdx.x * 32;         // first L4 node (m4=256/row)
  int b = g0 >> 8;
  int j4 = g0 & 255;
  const int* sym_b = symbols + (size_t)b * (N_ - 1);

  #pragma unroll
  for (int i = 0; i < 2; ++i) {
    int fid = t + 512 * i;
    int row = fid >> 4, co = (fid & 15) * 8;
    *(int4*)&Ag[row][co] = *(const int4*)(in_h8 + (size_t)(2 * g0 + row) * H_ + co);
  }
  __syncthreads();

  const short8* wf = (const short8*)Wfrag;
  #pragma unroll
  for (int c = 0; c < 2; ++c) {
    f32x4 acc[2][4];
    #pragma unroll
    for (int r = 0; r < 2; ++r)
      #pragma unroll
      for (int g = 0; g < 4; ++g) acc[r][g] = (f32x4){0.f, 0.f, 0.f, 0.f};
    #pragma unroll
    for (int K = 0; K < 4; ++K) {
      short8 bfr[4];
      #pragma unroll
      for (int g = 0; g < 4; ++g) bfr[g] = wf[(size_t)((w + 8 * g) * 4 + K) * 64 + L];
      short8 a0 = *(const short8*)&Ag[32 * c + cL][K * 32 + q * 8];
      short8 a1 = *(const short8*)&Ag[32 * c + 16 + cL][K * 32 + q * 8];
      #pragma unroll
      for (int g = 0; g < 4; ++g) {
        acc[0][g] = __builtin_amdgcn_mfma_f32_16x16x32_bf16(a0, bfr[g], acc[0][g], 0, 0, 0);
        acc[1][g] = __builtin_amdgcn_mfma_f32_16x16x32_bf16(a1, bfr[g], acc[1][g], 0, 0, 0);
      }
    }
    #pragma unroll
    for (int r = 0; r < 2; ++r) {
      #pragma unroll
      for (int nd = 0; nd < 2; ++nd) {
        int n = 16 * c + 8 * r + 2 * q + nd;
        int g = g0 + n;
        int s = sym_b[3584 + j4 + n];
        const float* sx = symx + (size_t)s * 512;
        Gates gt = gate_combine(sx, cc,
            acc[r][0][2 * nd] + acc[r][0][2 * nd + 1],
            acc[r][1][2 * nd] + acc[r][1][2 * nd + 1],
            acc[r][2][2 * nd] + acc[r][2][2 * nd + 1],
            acc[r][3][2 * nd], acc[r][3][2 * nd + 1],
            in_c[(size_t)(2 * g) * H_ + cc], in_c[(size_t)(2 * g + 1) * H_ + cc]);
        Bc[n][cc] = gt.cv;
        Bh[n][cc] = f2bf(gt.hv);
      }
    }
  }
  __syncthreads();
  {
    f32x4 acc[2][4];
    #pragma unroll
    for (int r = 0; r < 2; ++r)
      #pragma unroll
      for (int g = 0; g < 4; ++g) acc[r][g] = (f32x4){0.f, 0.f, 0.f, 0.f};
    #pragma unroll
    for (int K = 0; K < 4; ++K) {
      short8 bfr[4];
      #pragma unroll
      for (int g = 0; g < 4; ++g) bfr[g] = wf[(size_t)((w + 8 * g) * 4 + K) * 64 + L];
      short8 a0 = *(const short8*)&Bh[cL][K * 32 + q * 8];
      short8 a1 = *(const short8*)&Bh[16 + cL][K * 32 + q * 8];
      #pragma unroll
      for (int g = 0; g < 4; ++g) {
        acc[0][g] = __builtin_amdgcn_mfma_f32_16x16x32_bf16(a0, bfr[g], acc[0][g], 0, 0, 0);
        acc[1][g] = __builtin_amdgcn_mfma_f32_16x16x32_bf16(a1, bfr[g], acc[1][g], 0, 0, 0);
      }
    }
    #pragma unroll
    for (int r = 0; r < 2; ++r) {
      #pragma unroll
      for (int nd = 0; nd < 2; ++nd) {
        int n = 8 * r + 2 * q + nd;
        int G5 = (g0 >> 1) + n;
        int s = sym_b[3840 + (j4 >> 1) + n];
        const float* sx = symx + (size_t)s * 512;
        Gates gt = gate_combine(sx, cc,
            acc[r][0][2 * nd] + acc[r][0][2 * nd + 1],
            acc[r][1][2 * nd] + acc[r][1][2 * nd + 1],
            acc[r][2][2 * nd] + acc[r][2][2 * nd + 1],
            acc[r][3][2 * nd], acc[r][3][2 * nd + 1],
            Bc[2 * n][cc], Bc[2 * n + 1][cc]);
        c_out[(size_t)G5 * H_ + cc] = gt.cv;
        h_out8[(size_t)G5 * H_ + cc] = f2bf(gt.hv);
      }
    }
  }
}

// ---- dense level 6: 16 nodes/block, 512 threads ----
__global__ void __launch_bounds__(512, 2) k_lvl6(
    const unsigned short* __restrict__ Wfrag, const float* __restrict__ symx,
    const int* __restrict__ symbols,
    const unsigned short* __restrict__ h_prev8, const float* __restrict__ c_prev,
    unsigned short* __restrict__ h_out8, float* __restrict__ c_out) {
  __shared__ __align__(16) unsigned short Asm[32][136];
  int t = threadIdx.x;
  int w = t >> 6, L = t & 63, q = L >> 4, cL = L & 15;
  int g0 = blockIdx.x * 16;

  {
    int row = t >> 4, co = (t & 15) * 8;
    *(int4*)&Asm[row][co] = *(const int4*)(h_prev8 + (size_t)(2 * g0 + row) * H_ + co);
  }
  __syncthreads();

  f32x4 acc[2][4];
  #pragma unroll
  for (int r = 0; r < 2; ++r)
    #pragma unroll
    for (int g = 0; g < 4; ++g) acc[r][g] = (f32x4){0.f, 0.f, 0.f, 0.f};

  const short8* wf = (const short8*)Wfrag;
  #pragma unroll
  for (int K = 0; K < 4; ++K) {
    short8 bfr[4];
    #pragma unroll
    for (int g = 0; g < 4; ++g) bfr[g] = wf[(size_t)((w + 8 * g) * 4 + K) * 64 + L];
    short8 a0 = *(const short8*)&Asm[cL][K * 32 + q * 8];
    short8 a1 = *(const short8*)&Asm[16 + cL][K * 32 + q * 8];
    #pragma unroll
    for (int g = 0; g < 4; ++g) {
      acc[0][g] = __builtin_amdgcn_mfma_f32_16x16x32_bf16(a0, bfr[g], acc[0][g], 0, 0, 0);
      acc[1][g] = __builtin_amdgcn_mfma_f32_16x16x32_bf16(a1, bfr[g], acc[1][g], 0, 0, 0);
    }
  }

  int cc = 16 * w + cL;
  #pragma unroll
  for (int r = 0; r < 2; ++r) {
    #pragma unroll
    for (int nd = 0; nd < 2; ++nd) {
      int n = 8 * r + 2 * q + nd;
      int g = g0 + n;
      int bb = g >> 6, jj = g & 63;   // m6 = 64
      int s = symbols[bb * (N_ - 1) + 3968 + jj];
      const float* sx = symx + (size_t)s * 512;
      Gates gt = gate_combine(sx, cc,
          acc[r][0][2 * nd] + acc[r][0][2 * nd + 1],
          acc[r][1][2 * nd] + acc[r][1][2 * nd + 1],
          acc[r][2][2 * nd] + acc[r][2][2 * nd + 1],
          acc[r][3][2 * nd], acc[r][3][2 * nd + 1],
          c_prev[(size_t)(2 * g) * H_ + cc], c_prev[(size_t)(2 * g + 1) * H_ + cc]);
      c_out[(size_t)g * H_ + cc] = gt.cv;
      h_out8[(size_t)g * H_ + cc] = f2bf(gt.hv);
    }
  }
}

// ---- deep subtree kernel: levels 7-12, one block per batch row, 512 threads ----
__global__ void __launch_bounds__(512, 1) k_deep(
    const unsigned short* __restrict__ Wfrag, const float* __restrict__ symx,
    const int* __restrict__ symbols,
    const unsigned short* __restrict__ in_h8, const float* __restrict__ in_c,
    float* __restrict__ out_root) {
  __shared__ __align__(16) unsigned short Asm[64][136];
  __shared__ float Csm0[64][128];
  __shared__ float Csm1[32][128];
  int t = threadIdx.x;
  int w = t >> 6, L = t & 63, q = L >> 4, cL = L & 15;
  int b = blockIdx.x;

  #pragma unroll
  for (int i = 0; i < 2; ++i) {
    int fid = t + 512 * i;
    int row = fid >> 4, co = (fid & 15) * 8;
    *(int4*)&Asm[row][co] = *(const int4*)(in_h8 + (size_t)(b * 64 + row) * H_ + co);
  }
  #pragma unroll
  for (int i = 0; i < 4; ++i) {
    int fid = t + 512 * i;
    int row = fid >> 5, c4 = (fid & 31) << 2;
    *(float4*)&Csm0[row][c4] = *(const float4*)(in_c + (size_t)(b * 64 + row) * H_ + c4);
  }
  __syncthreads();

  const short8* wf = (const short8*)Wfrag;
  int cc = 16 * w + cL;
  int R = 64;
  #pragma unroll
  for (int lev = 0; lev < 6; ++lev) {
    const int l = 7 + lev;
    const int nodes = R >> 1;
    const int jb = b * (N_ - 1) + (N_ - (N_ >> (l - 1)));
    const int nchunk = (R + 31) >> 5;
    for (int c = 0; c < nchunk; ++c) {
      f32x4 acc[2][4];
      #pragma unroll
      for (int r = 0; r < 2; ++r)
        #pragma unroll
        for (int g = 0; g < 4; ++g) acc[r][g] = (f32x4){0.f, 0.f, 0.f, 0.f};
      #pragma unroll
      for (int K = 0; K < 4; ++K) {
        short8 bfr[4];
        #pragma unroll
        for (int g = 0; g < 4; ++g) bfr[g] = wf[(size_t)((w + 8 * g) * 4 + K) * 64 + L];
        short8 a0 = *(const short8*)&Asm[32 * c + cL][K * 32 + q * 8];
        short8 a1 = *(const short8*)&Asm[32 * c + 16 + cL][K * 32 + q * 8];
        #pragma unroll
        for (int g = 0; g < 4; ++g) {
          acc[0][g] = __builtin_amdgcn_mfma_f32_16x16x32_bf16(a0, bfr[g], acc[0][g], 0, 0, 0);
          acc[1][g] = __builtin_amdgcn_mfma_f32_16x16x32_bf16(a1, bfr[g], acc[1][g], 0, 0, 0);
        }
      }
      __syncthreads();
      const float* crd = (l & 1) ? &Csm0[0][0] : &Csm1[0][0];
      float* cwr = (l & 1) ? &Csm1[0][0] : &Csm0[0][0];
      #pragma unroll
      for (int r = 0; r < 2; ++r) {
        #pragma unroll
        for (int nd = 0; nd < 2; ++nd) {
          int n = 16 * c + 8 * r + 2 * q + nd;
          if (n < nodes) {
            int s = symbols[jb + n];
            const float* sx = symx + (size_t)s * 512;
            Gates gt = gate_combine(sx, cc,
                acc[r][0][2 * nd] + acc[r][0][2 * nd + 1],
                acc[r][1][2 * nd] + acc[r][1][2 * nd + 1],
                acc[r][2][2 * nd] + acc[r][2][2 * nd + 1],
                acc[r][3][2 * nd], acc[r][3][2 * nd + 1],
                crd[(size_t)(2 * n) * 128 + cc], crd[(size_t)(2 * n + 1) * 128 + cc]);
            if (lev == 5) {
              out_root[(size_t)b * H_ + cc] = gt.hv;
            } else {
              cwr[(size_t)n * 128 + cc] = gt.cv;
              Asm[n][cc] = f2bf(gt.hv);
            }
          }
        }
      }
      __syncthreads();
    }
    R >>= 1;
  }
}

// ---- final projection: out = root_h @ Wout.T + bout ----
__global__ void k_out(const float* __restrict__ hroot, const float* __restrict__ Wout,
                      const float* __restrict__ bout, float* __restrict__ out) {
  int b = blockIdx.x, o = threadIdx.x;
  __shared__ float hr[128];
  hr[o] = hroot[(size_t)b * H_ + o];
  __syncthreads();
  float acc = bout[o];
  for (int k = 0; k < H_; ++k) acc = fmaf(hr[k], Wout[o * H_ + k], acc);
  out[(size_t)b * H_ + o] = acc;
}

extern "C" void kernel_launch(void* const* d_in, const int* in_sizes, int n_in,
                              void* d_out, int out_size, void* d_ws, size_t ws_size,
                              hipStream_t stream) {
  const int* tokens    = (const int*)d_in[0];
  const int* symbols   = (const int*)d_in[1];
  const float* emb     = (const float*)d_in[2];
  const float* sym_emb = (const float*)d_in[3];
  const float* Wp  = (const float*)d_in[4];
  const float* bp  = (const float*)d_in[5];
  const float* Wi  = (const float*)d_in[6];
  const float* bi  = (const float*)d_in[7];
  const float* Ui  = (const float*)d_in[8];
  const float* Wf  = (const float*)d_in[9];
  const float* bf  = (const float*)d_in[10];
  const float* Uf  = (const float*)d_in[11];
  const float* Wo  = (const float*)d_in[12];
  const float* bo  = (const float*)d_in[13];
  const float* Uo  = (const float*)d_in[14];
  const float* Wu  = (const float*)d_in[15];
  const float* bu  = (const float*)d_in[16];
  const float* Uu  = (const float*)d_in[17];
  const float* Wout= (const float*)d_in[18];
  const float* bout= (const float*)d_in[19];

  // Workspace layout (~54 MB)
  char* ws = (char*)d_ws;
  unsigned short* Wfrag   = (unsigned short*)(ws);                  // 131072
  float*          Wt      = (float*)(ws + 131072);                  // 262144
  float*          Wxt     = (float*)(ws + 393216);                  // 262144
  float*          Wpt     = (float*)(ws + 655360);                  // 32768
  unsigned short* leaf_h8 = (unsigned short*)(ws + 688128);         // 5376
  float*          leaf_c  = (float*)(ws + 693504);                  // 10752
  float*          symx    = (float*)(ws + 704256);                  // 102400
  float*          za      = (float*)(ws + 806656);                  // 1128960
  unsigned short* tab_h8  = (unsigned short*)(ws + 1935616);        // 5644800
  float*          tab_c   = (float*)(ws + 7580416UL);               // 11289600
  int*            idx1    = (int*)(ws + 18870016UL);                // 524288
  float*          hroot   = (float*)(ws + 19394304UL);              // 32768
  unsigned short* L3h8    = (unsigned short*)(ws + 19427072UL);     // 8388608
  float*          L3c     = (float*)(ws + 27815680UL);              // 16777216
  unsigned short* L5h8    = (unsigned short*)(ws + 44592896UL);     // 2097152
  float*          L5c     = (float*)(ws + 46690048UL);              // 4194304
  unsigned short* L6h8    = (unsigned short*)(ws + 50884352UL);     // 1048576
  float*          L6c     = (float*)(ws + 51932928UL);              // 2097152

  k_pre0<<<97, 256, 0, stream>>>(Ui, Uo, Uu, Uf, Wi, Wo, Wu, Wf, Wp,
                                 Wfrag, Wt, Wxt, Wpt);
  k_pre1<<<V_ + S_, 128, 0, stream>>>(emb, sym_emb, Wpt, Wxt,
                                      bp, bi, bo, bu, bf, leaf_h8, leaf_c, symx);
  k_tabA<<<NPAIR, 128, 0, stream>>>(leaf_h8, Wt, za);
  k_tabB<<<NTAB / 2 + 512, 256, 0, stream>>>(za, symx, leaf_c, tokens, symbols,
                                             tab_h8, tab_c, idx1);
  k_lvl23<<<2048, 512, 0, stream>>>(Wfrag, symx, symbols, idx1, tab_h8, tab_c, L3h8, L3c);
  k_lvl45<<<512, 512, 0, stream>>>(Wfrag, symx, symbols, L3h8, L3c, L5h8, L5c);
  k_lvl6<<<256, 512, 0, stream>>>(Wfrag, symx, symbols, L5h8, L5c, L6h8, L6c);
  k_deep<<<B_, 512, 0, stream>>>(Wfrag, symx, symbols, L6h8, L6c, hroot);
  k_out<<<B_, 128, 0, stream>>>(hroot, Wout, bout, (float*)d_out);
}